// Round 1
// baseline (447.424 us; speedup 1.0000x reference)
//
#include <hip/hip_runtime.h>

// Problem constants: B=32, S=4096, H=512, E=512
typedef __attribute__((ext_vector_type(8))) short bf16x8;
typedef __attribute__((ext_vector_type(4))) float f32x4;

__device__ inline unsigned int cvt_pk_bf16(float lo, float hi){
  unsigned int r;
  asm("v_cvt_pk_bf16_f32 %0, %1, %2" : "=v"(r) : "v"(lo), "v"(hi));
  return r;
}

__device__ inline float fast_tanh(float x){
  // tanh(x) = 1 - 2/(exp(2x)+1); exp(2x) = exp2(x * 2*log2(e))
  float e = __builtin_amdgcn_exp2f(x * 2.8853900817779268f);
  return 1.0f - 2.0f * __builtin_amdgcn_rcpf(e + 1.0f);
}

// ---- K0: We [512][512] f32 -> bf16, laid out as 32 chunk images of [16][512]
// with XOR swizzle (byte ^= (row&7)<<4) so score_kernel can copy bytes verbatim
// into LDS and read ds_read_b128 fragments conflict-light.
__global__ __launch_bounds__(256) void we_conv(const float* __restrict__ We,
                                               unsigned int* __restrict__ weSwz){
  int gid = blockIdx.x * 256 + threadIdx.x;   // 32768 threads
  int n  = gid >> 6;        // row 0..511  (k-output index)
  int k8 = gid & 63;        // 8-element group along h
  const float4* src = (const float4*)(We + n*512 + k8*8);
  float4 f0 = src[0], f1 = src[1];
  unsigned int p0 = cvt_pk_bf16(f0.x, f0.y);
  unsigned int p1 = cvt_pk_bf16(f0.z, f0.w);
  unsigned int p2 = cvt_pk_bf16(f1.x, f1.y);
  unsigned int p3 = cvt_pk_bf16(f1.z, f1.w);
  int nc = n >> 4, r = n & 15;
  int byte = (k8*16) ^ ((r & 7) << 4);
  *(uint4*)((char*)weSwz + nc*16384 + r*1024 + byte) = make_uint4(p0,p1,p2,p3);
}

// ---- K1: gd[b][k] = h[b,:]·Wd[k,:] + bd[k] + be[k]   (be folded in here)
__global__ __launch_bounds__(256) void gd_kernel(const float* __restrict__ hvec,
                                                 const float* __restrict__ Wd,
                                                 const float* __restrict__ bd,
                                                 const float* __restrict__ be,
                                                 float* __restrict__ gd){
  __shared__ float hs[512];
  int b = blockIdx.x >> 2, kc = blockIdx.x & 3;   // 128 blocks
  int tid = threadIdx.x;
  hs[tid]       = hvec[b*512 + tid];
  hs[tid + 256] = hvec[b*512 + 256 + tid];
  __syncthreads();
  int k  = kc*128 + (tid >> 1);
  int hh = (tid & 1) * 256;
  const float4* wrow = (const float4*)(Wd + (size_t)k*512 + hh);
  const float4* hv4  = (const float4*)(hs + hh);
  float acc = 0.f;
  #pragma unroll 8
  for (int i = 0; i < 64; ++i){
    float4 w = wrow[i]; float4 u = hv4[i];
    acc += w.x*u.x + w.y*u.y + w.z*u.z + w.w*u.w;
  }
  acc += __shfl_xor(acc, 1);
  if ((tid & 1) == 0) gd[b*512 + k] = acc + bd[k] + be[k];
}

// ---- K2: fused scores[b,s] = sum_k tanh(ctx·We^T + gd)·Wv
// Block = 256 thr (4 waves), M-tile = 64 rows. A (ctx) staged to LDS bf16
// (swizzled), A-frags register-resident; We chunks [16][512] prefetched
// global->reg->LDS (T14). 16x16x32 bf16 MFMA, tanh+reduce epilogue in regs.
__global__ __launch_bounds__(256,2) void score_kernel(
    const float* __restrict__ ctx, const uint4* __restrict__ weSwz,
    const float* __restrict__ gd, const float* __restrict__ Wv,
    float* __restrict__ scores){
  __shared__ uint4 ldsbuf[5120];               // 80 KiB -> 2 blocks/CU
  char* ldsA = (char*)ldsbuf;                  // 64 KiB: [64 rows][1024 B] swizzled
  char* ldsB = (char*)ldsbuf + 65536;          // 16 KiB: one We chunk image

  const int tid  = threadIdx.x;
  const int bid  = blockIdx.x;                 // 2048
  const int row0 = bid * 64;                   // global row = b*4096 + s
  const int b    = row0 >> 12;

  // prefetch We chunk 0
  uint4 bpre[4];
  #pragma unroll
  for (int i = 0; i < 4; ++i) bpre[i] = weSwz[i*256 + tid];

  { // stage A tile: 64 rows x 512 h, f32 -> bf16, swizzled
    const int r = tid >> 2, q = tid & 3;
    const float4* src = (const float4*)(ctx + ((long)(row0 + r) << 9)) + q*32;
    char* rowBase = ldsA + r*1024;
    const int swz = (r & 7) << 4;
    #pragma unroll
    for (int i = 0; i < 16; ++i){
      float4 f0 = src[i*2], f1 = src[i*2+1];
      unsigned int p0 = cvt_pk_bf16(f0.x, f0.y);
      unsigned int p1 = cvt_pk_bf16(f0.z, f0.w);
      unsigned int p2 = cvt_pk_bf16(f1.x, f1.y);
      unsigned int p3 = cvt_pk_bf16(f1.z, f1.w);
      int byteInRow = ((q*128 + i*8) * 2) ^ swz;
      *(uint4*)(rowBase + byteInRow) = make_uint4(p0,p1,p2,p3);
    }
  }
  __syncthreads();

  const int wid  = tid >> 6;
  const int lane = tid & 63;
  const int lrow = lane & 15;    // A row within wave tile / B col (k-out)
  const int kgrp = lane >> 4;    // k-group 0..3

  // A-fragments: 16 K-steps, register-resident for whole block (64 VGPR)
  bf16x8 afrag[16];
  {
    const int arow = wid*16 + lrow;
    const char* aBase = ldsA + arow*1024;
    const int aswz = (arow & 7) << 4;
    #pragma unroll
    for (int t = 0; t < 16; ++t){
      int byte = ((t*32 + kgrp*8)*2) ^ aswz;
      afrag[t] = *(const bf16x8*)(aBase + byte);
    }
  }
  #pragma unroll
  for (int i = 0; i < 4; ++i) *(uint4*)(ldsB + (i*256 + tid)*16) = bpre[i];
  __syncthreads();

  float sc0=0.f, sc1=0.f, sc2=0.f, sc3=0.f;
  const char* bBase = ldsB + lrow*1024;
  const int bswz = (lrow & 7) << 4;

  for (int nc = 0; nc < 32; ++nc){
    if (nc < 31){                       // T14: issue next-chunk loads early
      #pragma unroll
      for (int i = 0; i < 4; ++i) bpre[i] = weSwz[(nc+1)*1024 + i*256 + tid];
    }
    int col = nc*16 + lrow;             // global k-output index
    float gdv = gd[b*512 + col];
    float wvv = Wv[col];
    f32x4 acc = {0.f,0.f,0.f,0.f};
    #pragma unroll
    for (int t = 0; t < 16; ++t){
      int byte = ((t*32 + kgrp*8)*2) ^ bswz;
      bf16x8 bfrag = *(const bf16x8*)(bBase + byte);
      acc = __builtin_amdgcn_mfma_f32_16x16x32_bf16(afrag[t], bfrag, acc, 0, 0, 0);
    }
    // D element (m,n): m = kgrp*4 + j (row), n = lrow (col) [m89 layout]
    sc0 += fast_tanh(acc[0] + gdv) * wvv;
    sc1 += fast_tanh(acc[1] + gdv) * wvv;
    sc2 += fast_tanh(acc[2] + gdv) * wvv;
    sc3 += fast_tanh(acc[3] + gdv) * wvv;
    __syncthreads();                    // everyone done reading ldsB
    if (nc < 31){
      #pragma unroll
      for (int i = 0; i < 4; ++i) *(uint4*)(ldsB + (i*256 + tid)*16) = bpre[i];
    }
    __syncthreads();                    // chunk nc+1 staged
  }

  // reduce over the 16 n-columns (lanes sharing kgrp are contiguous 16)
  #pragma unroll
  for (int m = 1; m < 16; m <<= 1){
    sc0 += __shfl_xor(sc0, m);
    sc1 += __shfl_xor(sc1, m);
    sc2 += __shfl_xor(sc2, m);
    sc3 += __shfl_xor(sc3, m);
  }
  if (lrow == 0){
    int r = row0 + wid*16 + kgrp*4;
    *(float4*)(scores + r) = make_float4(sc0, sc1, sc2, sc3);
  }
}

// ---- K3: softmax over S=4096 per batch row (bv dropped: shift-invariant)
__global__ __launch_bounds__(256) void softmax_kernel(const float* __restrict__ scores,
                                                      float* __restrict__ weights){
  __shared__ float red[8];
  int b = blockIdx.x, tid = threadIdx.x;
  const float4* src = (const float4*)(scores + b*4096);
  float4* dst = (float4*)(weights + b*4096);
  float4 v[4];
  float m = -1e30f;
  #pragma unroll
  for (int i = 0; i < 4; ++i){
    v[i] = src[tid + i*256];
    m = fmaxf(m, fmaxf(fmaxf(v[i].x, v[i].y), fmaxf(v[i].z, v[i].w)));
  }
  #pragma unroll
  for (int o = 1; o < 64; o <<= 1) m = fmaxf(m, __shfl_xor(m, o));
  if ((tid & 63) == 0) red[tid >> 6] = m;
  __syncthreads();
  m = fmaxf(fmaxf(red[0], red[1]), fmaxf(red[2], red[3]));
  float s = 0.f;
  #pragma unroll
  for (int i = 0; i < 4; ++i){
    v[i].x = __builtin_amdgcn_exp2f((v[i].x - m) * 1.4426950408889634f);
    v[i].y = __builtin_amdgcn_exp2f((v[i].y - m) * 1.4426950408889634f);
    v[i].z = __builtin_amdgcn_exp2f((v[i].z - m) * 1.4426950408889634f);
    v[i].w = __builtin_amdgcn_exp2f((v[i].w - m) * 1.4426950408889634f);
    s += v[i].x + v[i].y + v[i].z + v[i].w;
  }
  #pragma unroll
  for (int o = 1; o < 64; o <<= 1) s += __shfl_xor(s, o);
  if ((tid & 63) == 0) red[4 + (tid >> 6)] = s;
  __syncthreads();
  s = red[4] + red[5] + red[6] + red[7];
  float inv = 1.0f / s;
  #pragma unroll
  for (int i = 0; i < 4; ++i){
    v[i].x *= inv; v[i].y *= inv; v[i].z *= inv; v[i].w *= inv;
    dst[tid + i*256] = v[i];
  }
}

// ---- K4: c_t partials (deterministic two-stage, no float atomics)
__global__ __launch_bounds__(256) void ct_partial(const float* __restrict__ ctx,
                                                  const float* __restrict__ wbuf,
                                                  float* __restrict__ part){
  int bid = blockIdx.x;            // 512: b = bid>>4, 256-row s-chunk = bid&15
  int b = bid >> 4, ch = bid & 15;
  int tid = threadIdx.x;
  int hq = tid & 127;              // float4 index along h
  int sh = tid >> 7;               // 0/1: two s-streams
  const float* wrow = wbuf + b*4096 + ch*256;
  const float4* src = (const float4*)(ctx + ((size_t)b*4096 + (size_t)ch*256)*512) + hq;
  float4 acc = {0.f,0.f,0.f,0.f};
  #pragma unroll 8
  for (int s = sh; s < 256; s += 2){
    float w = wrow[s];
    float4 c = src[(size_t)s*128];
    acc.x += w*c.x; acc.y += w*c.y; acc.z += w*c.z; acc.w += w*c.w;
  }
  ((float4*)(part + (size_t)bid*1024 + sh*512))[hq] = acc;
}

__global__ __launch_bounds__(128) void ct_reduce(const float* __restrict__ part,
                                                 float* __restrict__ ct){
  int b = blockIdx.x, tid = threadIdx.x;   // 128 threads, float4 over h
  const float4* p = (const float4*)(part + (size_t)b*16384) + tid;
  float4 acc = {0.f,0.f,0.f,0.f};
  #pragma unroll
  for (int g = 0; g < 32; ++g){
    float4 v = p[g*128];
    acc.x += v.x; acc.y += v.y; acc.z += v.z; acc.w += v.w;
  }
  ((float4*)(ct + b*512))[tid] = acc;
}

// ---- K5: r_t = [c_t,h,x]·Wr^T + br; maxout pairs -> output [32][512]
__global__ __launch_bounds__(256) void final_kernel(
    const float* __restrict__ ct, const float* __restrict__ hvec,
    const float* __restrict__ x, const float* __restrict__ Wr,
    const float* __restrict__ br, float* __restrict__ out){
  __shared__ float xs[8][1536];            // 48 KiB: concat vectors for 8 b
  int bt = blockIdx.x >> 4;                // 0..3
  int it = blockIdx.x & 15;                // 0..15
  int tid = threadIdx.x;
  int b0 = bt * 8;
  for (int idx = tid; idx < 8*1536; idx += 256){
    int bl = idx / 1536, j = idx % 1536;
    int b = b0 + bl;
    float v = (j < 512) ? ct[b*512 + j]
            : (j < 1024) ? hvec[b*512 + (j - 512)]
            : x[b*512 + (j - 1024)];
    xs[bl][j] = v;
  }
  __syncthreads();
  int i = it*64 + (tid & 63);
  int bl0 = (tid >> 6) * 2;
  const float4* wrow = (const float4*)(Wr + (size_t)i*1536);
  const float4* x0 = (const float4*)xs[bl0];
  const float4* x1 = (const float4*)xs[bl0 + 1];
  float a0 = 0.f, a1 = 0.f;
  #pragma unroll 4
  for (int k = 0; k < 384; ++k){
    float4 w = wrow[k];
    float4 u0 = x0[k], u1 = x1[k];
    a0 += w.x*u0.x + w.y*u0.y + w.z*u0.z + w.w*u0.w;
    a1 += w.x*u1.x + w.y*u1.y + w.z*u1.z + w.w*u1.w;
  }
  float bias = br[i];
  a0 += bias; a1 += bias;
  float n0 = __shfl_xor(a0, 1);
  float n1 = __shfl_xor(a1, 1);
  if ((tid & 1) == 0){
    out[(b0 + bl0    )*512 + (i >> 1)] = fmaxf(a0, n0);
    out[(b0 + bl0 + 1)*512 + (i >> 1)] = fmaxf(a1, n1);
  }
}

extern "C" void kernel_launch(void* const* d_in, const int* in_sizes, int n_in,
                              void* d_out, int out_size, void* d_ws, size_t ws_size,
                              hipStream_t stream){
  const float* ctx  = (const float*)d_in[0];
  const float* hvec = (const float*)d_in[1];
  const float* x    = (const float*)d_in[2];
  const float* We   = (const float*)d_in[3];
  const float* be   = (const float*)d_in[4];
  const float* Wd   = (const float*)d_in[5];
  const float* bd   = (const float*)d_in[6];
  const float* Wv   = (const float*)d_in[7];
  // d_in[8] = bv: dropped (softmax shift-invariance)
  const float* Wr   = (const float*)d_in[9];
  const float* br   = (const float*)d_in[10];

  float* out     = (float*)d_out;        // output [32][512]
  float* weights = out + 32*512;         // weights [32][4096]

  char* ws = (char*)d_ws;
  unsigned int* weSwz = (unsigned int*)ws;             // 512 KiB
  float* scores = (float*)(ws + (512 << 10));          // 512 KiB
  float* part   = (float*)(ws + (1024 << 10));         // 2 MiB
  float* ct     = (float*)(ws + (3 << 20));            // 64 KiB
  float* gd     = (float*)(ws + (3 << 20) + (64 << 10)); // 64 KiB

  we_conv<<<128, 256, 0, stream>>>(We, weSwz);
  gd_kernel<<<128, 256, 0, stream>>>(hvec, Wd, bd, be, gd);
  score_kernel<<<2048, 256, 0, stream>>>(ctx, (const uint4*)weSwz, gd, Wv, scores);
  softmax_kernel<<<32, 256, 0, stream>>>(scores, weights);
  ct_partial<<<512, 256, 0, stream>>>(ctx, weights, part);
  ct_reduce<<<32, 128, 0, stream>>>(part, ct);
  final_kernel<<<64, 256, 0, stream>>>(ct, hvec, x, Wr, br, out);
}

// Round 2
// 219.624 us; speedup vs baseline: 2.0372x; 2.0372x over previous
//
#include <hip/hip_runtime.h>

// Problem constants: B=32, S=4096, H=512, E=512
typedef __attribute__((ext_vector_type(8))) short bf16x8;
typedef __attribute__((ext_vector_type(16))) float f32x16;

typedef __attribute__((address_space(3))) unsigned int lds_u32;
typedef __attribute__((address_space(1))) unsigned int glb_u32;

__device__ inline unsigned int cvt_pk_bf16(float lo, float hi){
  unsigned int r;
  asm("v_cvt_pk_bf16_f32 %0, %1, %2" : "=v"(r) : "v"(lo), "v"(hi));
  return r;
}
__device__ inline bf16x8 pack8(float4 a, float4 b){
  union { unsigned int u[4]; bf16x8 v; } r;
  r.u[0]=cvt_pk_bf16(a.x,a.y); r.u[1]=cvt_pk_bf16(a.z,a.w);
  r.u[2]=cvt_pk_bf16(b.x,b.y); r.u[3]=cvt_pk_bf16(b.z,b.w);
  return r.v;
}
__device__ inline float fast_tanh(float x){
  float e = __builtin_amdgcn_exp2f(x * 2.8853900817779268f);
  return 1.0f - 2.0f * __builtin_amdgcn_rcpf(e + 1.0f);
}

// ---- K0: We [512][512] f32 -> bf16 fragment images for mfma_32x32x16.
// weFrag[hc][t][lane] (16B): col=(hc>>1)*32+(lane&31), k=(hc&1)*256+t*16+(lane>>5)*8+j
// Lane-linear 16B records: global_load_lds verbatim + conflict-free ds_read_b128.
__global__ __launch_bounds__(256) void we_conv(const float* __restrict__ We,
                                               uint4* __restrict__ weFrag){
  int gid = blockIdx.x * 256 + threadIdx.x;   // 32768 = 32 hc x 16 t x 64 lanes
  int l  = gid & 63;
  int hc = gid >> 10;
  int colv = (hc >> 1)*32 + (l & 31);
  int k = ((hc & 1) << 8) + ((gid >> 6) & 15)*16 + (l >> 5)*8;
  const float4* src = (const float4*)(We + colv*512 + k);
  float4 f0 = src[0], f1 = src[1];
  weFrag[gid] = make_uint4(cvt_pk_bf16(f0.x,f0.y), cvt_pk_bf16(f0.z,f0.w),
                           cvt_pk_bf16(f1.x,f1.y), cvt_pk_bf16(f1.z,f1.w));
}

// ---- K1: gd[b][k] = h[b,:]·Wd[k,:] + bd[k] + be[k]
__global__ __launch_bounds__(256) void gd_kernel(const float* __restrict__ hvec,
                                                 const float* __restrict__ Wd,
                                                 const float* __restrict__ bd,
                                                 const float* __restrict__ be,
                                                 float* __restrict__ gd){
  __shared__ float hs[512];
  int b = blockIdx.x >> 2, kc = blockIdx.x & 3;
  int tid = threadIdx.x;
  hs[tid]       = hvec[b*512 + tid];
  hs[tid + 256] = hvec[b*512 + 256 + tid];
  __syncthreads();
  int k  = kc*128 + (tid >> 1);
  int hh = (tid & 1) * 256;
  const float4* wrow = (const float4*)(Wd + (size_t)k*512 + hh);
  const float4* hv4  = (const float4*)(hs + hh);
  float acc = 0.f;
  #pragma unroll 8
  for (int i = 0; i < 64; ++i){
    float4 w = wrow[i]; float4 u = hv4[i];
    acc += w.x*u.x + w.y*u.y + w.z*u.z + w.w*u.w;
  }
  acc += __shfl_xor(acc, 1);
  if ((tid & 1) == 0) gd[b*512 + k] = acc + bd[k] + be[k];
}

// ---- K2: fused scores. 4 waves x 32 rows = 128 rows/block, 1024 blocks.
// A-frags global->reg (bf16, resident). B staged via global_load_lds into a
// 3x16KB rotation, 1 barrier + counted vmcnt per 16KB half-chunk (T3/T4).
__global__ __launch_bounds__(256, 2) void score_kernel(
    const float* __restrict__ ctx, const char* __restrict__ weFrag,
    const float* __restrict__ gd, const float* __restrict__ Wv,
    float* __restrict__ scores){
  __shared__ char lds[3*16384 + 4096];       // 52 KiB -> 2 blocks/CU
  float* gdwv = (float*)(lds + 49152);       // [512 gd][512 Wv]

  const int tid  = threadIdx.x;
  const int wid  = tid >> 6;
  const int lane = tid & 63;
  const int bid  = blockIdx.x;
  const int row0 = bid * 128;
  const int b    = bid >> 5;                 // 32 blocks per batch row
  const int col  = lane & 31;
  const int hi   = lane >> 5;

  // stage gd + Wv into LDS (keeps the k-loop free of compiler VMEM)
  if (tid < 128) ((float4*)gdwv)[tid] = ((const float4*)(gd + b*512))[tid];
  else           ((float4*)gdwv)[tid] = ((const float4*)Wv)[tid - 128];

  // A-fragments: 32 k-steps, register-resident (128 VGPR)
  bf16x8 afrag[32];
  {
    const float4* ap = (const float4*)(ctx + (size_t)(row0 + wid*32 + col)*512 + hi*8);
    #pragma unroll
    for (int t = 0; t < 32; ++t)
      afrag[t] = pack8(ap[t*4], ap[t*4 + 1]);
  }

  asm volatile("s_waitcnt lgkmcnt(0)" ::: "memory");  // gdwv ds_writes done

  #define ISSUE(HC, BUF) do { \
    const char* _g = weFrag + ((size_t)(HC))*16384 + wid*4096; \
    char* _l = lds + (BUF)*16384 + wid*4096; \
    _Pragma("unroll") \
    for (int _i = 0; _i < 4; ++_i) \
      __builtin_amdgcn_global_load_lds((const glb_u32*)(_g + _i*1024 + lane*16), \
                                       (lds_u32*)(_l + _i*1024), 16, 0, 0); \
  } while(0)

  ISSUE(0, 0);
  ISSUE(1, 1);

  f32x16 acc;
  float sc[16];
  #pragma unroll
  for (int r = 0; r < 16; ++r) sc[r] = 0.f;

  for (int nc = 0; nc < 16; ++nc){
    const int hc0 = 2*nc, hc1 = 2*nc + 1;

    // ---- half 0 (k = 0..255)
    asm volatile("s_waitcnt vmcnt(4)" ::: "memory");
    __builtin_amdgcn_s_barrier();             // hc0 landed (all waves); hc0-1 reads done
    if (hc0 < 30) ISSUE(hc0 + 2, (hc0 + 2) % 3);
    {
      const char* bb = lds + (hc0 % 3)*16384 + lane*16;
      #pragma unroll
      for (int r = 0; r < 16; ++r) acc[r] = 0.f;
      __builtin_amdgcn_s_setprio(1);
      #pragma unroll
      for (int t = 0; t < 16; ++t){
        bf16x8 bf = *(const bf16x8*)(bb + t*1024);
        acc = __builtin_amdgcn_mfma_f32_32x32x16_bf16(afrag[t], bf, acc, 0, 0, 0);
      }
      __builtin_amdgcn_s_setprio(0);
    }

    // ---- half 1 (k = 256..511)
    if (nc < 15) asm volatile("s_waitcnt vmcnt(4)" ::: "memory");
    else         asm volatile("s_waitcnt vmcnt(0)" ::: "memory");
    __builtin_amdgcn_s_barrier();
    if (hc1 < 30) ISSUE(hc1 + 2, (hc1 + 2) % 3);
    {
      const char* bb = lds + (hc1 % 3)*16384 + lane*16;
      __builtin_amdgcn_s_setprio(1);
      #pragma unroll
      for (int t = 0; t < 16; ++t){
        bf16x8 bf = *(const bf16x8*)(bb + t*1024);
        acc = __builtin_amdgcn_mfma_f32_32x32x16_bf16(afrag[16 + t], bf, acc, 0, 0, 0);
      }
      __builtin_amdgcn_s_setprio(0);
    }

    // ---- epilogue: sc[r] += tanh(acc + gd) * Wv   (col = nc*32 + lane&31)
    {
      float gdv = gdwv[nc*32 + col];
      float wvv = gdwv[512 + nc*32 + col];
      #pragma unroll
      for (int r = 0; r < 16; ++r)
        sc[r] += fast_tanh(acc[r] + gdv) * wvv;
    }
  }
  #undef ISSUE

  // reduce over the 32 columns (lanes 0-31 / 32-63 hold distinct rows)
  #pragma unroll
  for (int r = 0; r < 16; ++r){
    #pragma unroll
    for (int m = 1; m <= 16; m <<= 1) sc[r] += __shfl_xor(sc[r], m);
  }
  if (col == 0){
    float* so = scores + row0 + wid*32 + 4*hi;
    #pragma unroll
    for (int r = 0; r < 16; ++r)
      so[(r & 3) + 8*(r >> 2)] = sc[r];       // D row = (r&3)+8*(r>>2)+4*hi
  }
}

// ---- K3: softmax over S=4096 per batch row (bv dropped: shift-invariant)
__global__ __launch_bounds__(256) void softmax_kernel(const float* __restrict__ scores,
                                                      float* __restrict__ weights){
  __shared__ float red[8];
  int b = blockIdx.x, tid = threadIdx.x;
  const float4* src = (const float4*)(scores + b*4096);
  float4* dst = (float4*)(weights + b*4096);
  float4 v[4];
  float m = -1e30f;
  #pragma unroll
  for (int i = 0; i < 4; ++i){
    v[i] = src[tid + i*256];
    m = fmaxf(m, fmaxf(fmaxf(v[i].x, v[i].y), fmaxf(v[i].z, v[i].w)));
  }
  #pragma unroll
  for (int o = 1; o < 64; o <<= 1) m = fmaxf(m, __shfl_xor(m, o));
  if ((tid & 63) == 0) red[tid >> 6] = m;
  __syncthreads();
  m = fmaxf(fmaxf(red[0], red[1]), fmaxf(red[2], red[3]));
  float s = 0.f;
  #pragma unroll
  for (int i = 0; i < 4; ++i){
    v[i].x = __builtin_amdgcn_exp2f((v[i].x - m) * 1.4426950408889634f);
    v[i].y = __builtin_amdgcn_exp2f((v[i].y - m) * 1.4426950408889634f);
    v[i].z = __builtin_amdgcn_exp2f((v[i].z - m) * 1.4426950408889634f);
    v[i].w = __builtin_amdgcn_exp2f((v[i].w - m) * 1.4426950408889634f);
    s += v[i].x + v[i].y + v[i].z + v[i].w;
  }
  #pragma unroll
  for (int o = 1; o < 64; o <<= 1) s += __shfl_xor(s, o);
  if ((tid & 63) == 0) red[4 + (tid >> 6)] = s;
  __syncthreads();
  s = red[4] + red[5] + red[6] + red[7];
  float inv = 1.0f / s;
  #pragma unroll
  for (int i = 0; i < 4; ++i){
    v[i].x *= inv; v[i].y *= inv; v[i].z *= inv; v[i].w *= inv;
    dst[tid + i*256] = v[i];
  }
}

// ---- K4: c_t partials (deterministic two-stage, no float atomics)
__global__ __launch_bounds__(256) void ct_partial(const float* __restrict__ ctx,
                                                  const float* __restrict__ wbuf,
                                                  float* __restrict__ part){
  int bid = blockIdx.x;            // 512: b = bid>>4, 256-row s-chunk = bid&15
  int b = bid >> 4, ch = bid & 15;
  int tid = threadIdx.x;
  int hq = tid & 127;
  int sh = tid >> 7;
  const float* wrow = wbuf + b*4096 + ch*256;
  const float4* src = (const float4*)(ctx + ((size_t)b*4096 + (size_t)ch*256)*512) + hq;
  float4 acc = {0.f,0.f,0.f,0.f};
  #pragma unroll 8
  for (int s = sh; s < 256; s += 2){
    float w = wrow[s];
    float4 c = src[(size_t)s*128];
    acc.x += w*c.x; acc.y += w*c.y; acc.z += w*c.z; acc.w += w*c.w;
  }
  ((float4*)(part + (size_t)bid*1024 + sh*512))[hq] = acc;
}

__global__ __launch_bounds__(128) void ct_reduce(const float* __restrict__ part,
                                                 float* __restrict__ ct){
  int b = blockIdx.x, tid = threadIdx.x;
  const float4* p = (const float4*)(part + (size_t)b*16384) + tid;
  float4 acc = {0.f,0.f,0.f,0.f};
  #pragma unroll
  for (int g = 0; g < 32; ++g){
    float4 v = p[g*128];
    acc.x += v.x; acc.y += v.y; acc.z += v.z; acc.w += v.w;
  }
  ((float4*)(ct + b*512))[tid] = acc;
}

// ---- K5: r_t = [c_t,h,x]·Wr^T + br; maxout pairs -> output [32][512]
__global__ __launch_bounds__(256) void final_kernel(
    const float* __restrict__ ct, const float* __restrict__ hvec,
    const float* __restrict__ x, const float* __restrict__ Wr,
    const float* __restrict__ br, float* __restrict__ out){
  __shared__ float xs[8][1536];
  int bt = blockIdx.x >> 4;
  int it = blockIdx.x & 15;
  int tid = threadIdx.x;
  int b0 = bt * 8;
  for (int idx = tid; idx < 8*1536; idx += 256){
    int bl = idx / 1536, j = idx % 1536;
    int b = b0 + bl;
    float v = (j < 512) ? ct[b*512 + j]
            : (j < 1024) ? hvec[b*512 + (j - 512)]
            : x[b*512 + (j - 1024)];
    xs[bl][j] = v;
  }
  __syncthreads();
  int i = it*64 + (tid & 63);
  int bl0 = (tid >> 6) * 2;
  const float4* wrow = (const float4*)(Wr + (size_t)i*1536);
  const float4* x0 = (const float4*)xs[bl0];
  const float4* x1 = (const float4*)xs[bl0 + 1];
  float a0 = 0.f, a1 = 0.f;
  #pragma unroll 4
  for (int k = 0; k < 384; ++k){
    float4 w = wrow[k];
    float4 u0 = x0[k], u1 = x1[k];
    a0 += w.x*u0.x + w.y*u0.y + w.z*u0.z + w.w*u0.w;
    a1 += w.x*u1.x + w.y*u1.y + w.z*u1.z + w.w*u1.w;
  }
  float bias = br[i];
  a0 += bias; a1 += bias;
  float n0 = __shfl_xor(a0, 1);
  float n1 = __shfl_xor(a1, 1);
  if ((tid & 1) == 0){
    out[(b0 + bl0    )*512 + (i >> 1)] = fmaxf(a0, n0);
    out[(b0 + bl0 + 1)*512 + (i >> 1)] = fmaxf(a1, n1);
  }
}

extern "C" void kernel_launch(void* const* d_in, const int* in_sizes, int n_in,
                              void* d_out, int out_size, void* d_ws, size_t ws_size,
                              hipStream_t stream){
  const float* ctx  = (const float*)d_in[0];
  const float* hvec = (const float*)d_in[1];
  const float* x    = (const float*)d_in[2];
  const float* We   = (const float*)d_in[3];
  const float* be   = (const float*)d_in[4];
  const float* Wd   = (const float*)d_in[5];
  const float* bd   = (const float*)d_in[6];
  const float* Wv   = (const float*)d_in[7];
  // d_in[8] = bv: dropped (softmax shift-invariance)
  const float* Wr   = (const float*)d_in[9];
  const float* br   = (const float*)d_in[10];

  float* out     = (float*)d_out;        // output [32][512]
  float* weights = out + 32*512;         // weights [32][4096]

  char* ws = (char*)d_ws;
  char* weFrag  = ws;                                   // 512 KiB
  float* scores = (float*)(ws + (512 << 10));           // 512 KiB
  float* part   = (float*)(ws + (1024 << 10));          // 2 MiB
  float* ct     = (float*)(ws + (3 << 20));             // 64 KiB
  float* gd     = (float*)(ws + (3 << 20) + (64 << 10)); // 64 KiB

  we_conv<<<128, 256, 0, stream>>>(We, (uint4*)weFrag);
  gd_kernel<<<128, 256, 0, stream>>>(hvec, Wd, bd, be, gd);
  score_kernel<<<1024, 256, 0, stream>>>(ctx, weFrag, gd, Wv, scores);
  softmax_kernel<<<32, 256, 0, stream>>>(scores, weights);
  ct_partial<<<512, 256, 0, stream>>>(ctx, weights, part);
  ct_reduce<<<32, 128, 0, stream>>>(part, ct);
  final_kernel<<<64, 256, 0, stream>>>(ct, hvec, x, Wr, br, out);
}